// Round 8
// baseline (580.809 us; speedup 1.0000x reference)
//
#include <hip/hip_runtime.h>
#include <hip/hip_bf16.h>

typedef __bf16 bf16_t;
typedef __bf16 bf16x8 __attribute__((ext_vector_type(8)));
typedef float f32x4 __attribute__((ext_vector_type(4)));

#define DEVI static __device__ __forceinline__

static constexpr int E_ = 8, C_ = 1024, DIN = 4096, DOUT = 1024, TOK = 4096;
static constexpr int BM = 128, BN = 128, BK = 64;
static constexpr int NT = 512;                 // expert: 8 waves / block (R3 champion)

// ---- workspace layout (bytes) ----
static constexpr size_t WS_WT  = 0;                                      // [E][DOUT][DIN] bf16 (swizzled)
static constexpr size_t WS_RWT = WS_WT  + (size_t)E_ * DOUT * DIN * 2;   // [DOUT][DIN] bf16 (swizzled)
static constexpr size_t WS_EOT = WS_RWT + (size_t)DOUT * DIN * 2;        // [DOUT][E*C] bf16 (swizzled)

// XOR-swizzle within each 64-element K-group: chunk(col>>3 & 7) ^= row&7.
// Pre-applied to the GLOBAL layout of bf16 ws operands (rule 21).
DEVI int swz(int row, int col) {
    return (col & ~63) | ((col & 56) ^ ((row & 7) << 3)) | (col & 7);
}

// ============ prepass: transpose + cast weights to bf16 [out][in], swizzled ============
__global__ __launch_bounds__(256)
void transpose_cast_kernel(const float* __restrict__ expert_w,
                           const float* __restrict__ residual_w,
                           bf16_t* __restrict__ wt, bf16_t* __restrict__ rwt)
{
    __shared__ float tile[32][33];
    const int z = blockIdx.z;
    const float* src;
    bf16_t* dst;
    if (z < 8) { src = expert_w + (size_t)z * DIN * DOUT; dst = wt + (size_t)z * DOUT * DIN; }
    else       { src = residual_w;                         dst = rwt; }
    const int c0 = blockIdx.x * 32;   // col in src  (DOUT dim -> dst row)
    const int r0 = blockIdx.y * 32;   // row in src  (DIN dim  -> dst col/K)
    const int tx = threadIdx.x, ty = threadIdx.y;  // 32 x 8
#pragma unroll
    for (int k = 0; k < 4; ++k)
        tile[ty + 8 * k][tx] = src[(size_t)(r0 + ty + 8 * k) * DOUT + c0 + tx];
    __syncthreads();
#pragma unroll
    for (int k = 0; k < 4; ++k) {
        const int row = c0 + ty + 8 * k;      // DOUT
        const int col = r0 + tx;              // DIN (K)
        dst[(size_t)row * DIN + swz(row, col)] = (bf16_t)tile[tx][ty + 8 * k];
    }
}

// ============ LDS staging ============
// bf16 ws operand, pre-swizzled source: linear DMA copy. NW = waves/block.
template<int NELEM, int NW>
DEVI void stage_bf16(bf16_t* lds, const bf16_t* g, int ld, int tid)
{
    constexpr int PER_WAVE = NELEM / NW;
    constexpr int NI = PER_WAVE / 512;
    const int w = tid >> 6, l = tid & 63;
#pragma unroll
    for (int i = 0; i < NI; ++i) {
        const int eoff = w * PER_WAVE + i * 512 + l * 8;
        const int r = eoff >> 6, c = eoff & 63;
        const bf16_t* gp = g + (size_t)r * ld + c;
        bf16_t* lp = lds + w * PER_WAVE + i * 512;   // wave-uniform base; HW adds lane*16B
        __builtin_amdgcn_global_load_lds(
            (const __attribute__((address_space(1))) void*)gp,
            (__attribute__((address_space(3))) void*)lp, 16, 0, 0);
    }
}

// f32 operand: reg-stage + cvt + swizzled ds_write (expert kernel, 8 waves)
template<int NELEM>
DEVI void stage_f32(bf16_t* lds, const float* __restrict__ g, int ld, int tid)
{
    constexpr int NI = NELEM / (NT * 8);
#pragma unroll
    for (int i = 0; i < NI; ++i) {
        const int eoff = i * NT * 8 + tid * 8;
        const int r = eoff >> 6, c = eoff & 63;        // c is 8-aligned
        const float* gp = g + (size_t)r * ld + c;
        f32x4 v0 = *(const f32x4*)(gp);
        f32x4 v1 = *(const f32x4*)(gp + 4);
        bf16x8 h;
        h[0] = (bf16_t)v0[0]; h[1] = (bf16_t)v0[1];
        h[2] = (bf16_t)v0[2]; h[3] = (bf16_t)v0[3];
        h[4] = (bf16_t)v1[0]; h[5] = (bf16_t)v1[1];
        h[6] = (bf16_t)v1[2]; h[7] = (bf16_t)v1[3];
        const int cs = (c & 56) ^ ((r & 7) << 3);
        *(bf16x8*)(lds + r * 64 + cs) = h;
    }
}

// ============ expert GEMM: EOT[m][e*C+c] = sum_d WT_e[m][d]*front_e[c][d] + b ============
// (unchanged R3 champion)
__global__ __launch_bounds__(NT, 4)
void expert_gemm(const bf16_t* __restrict__ WT, const float* __restrict__ inputs,
                 bf16_t* __restrict__ EOT, const float* __restrict__ expert_b)
{
    __shared__ bf16_t As[BM * BK];
    __shared__ bf16_t Bs[BN * BK];
    const int tid = threadIdx.x;

    // T1: bijective XCD-chunked swizzle. nwg = 512 -> chunk k = expert k.
    int id = blockIdx.x + 8 * (blockIdx.y + 8 * blockIdx.z);
    id = (id & 7) * 64 + (id >> 3);
    const int bx = id & 7, by = (id >> 3) & 7, e = id >> 6;

    const int brow = by * BM;   // DOUT
    const int bcol = bx * BN;   // C
    const bf16_t* A = WT + (size_t)e * DOUT * DIN + (size_t)brow * DIN;
    const float*  B = inputs + (size_t)e * C_ * DIN + (size_t)bcol * DIN;

    const int w = tid >> 6, l = tid & 63;
    const int wr = (w >> 1) * 32, wc = (w & 1) * 64;   // wave tile 32x64
    const int lr = l & 15, lk = l >> 4, sw = (l & 7) << 3;

    f32x4 acc[2][4] = {};

    for (int k0 = 0; k0 < DIN; k0 += BK) {
        stage_bf16<BM * BK, 8>(As, A + k0, DIN, tid);
        stage_f32<BN * BK>(Bs, B + k0, DIN, tid);
        __syncthreads();
#pragma unroll
        for (int kk = 0; kk < 2; ++kk) {
            const int cs = (kk * 32 + lk * 8) ^ sw;
            bf16x8 a[2], b[4];
#pragma unroll
            for (int m = 0; m < 2; ++m)
                a[m] = *(const bf16x8*)(&As[(wr + m * 16 + lr) * BK + cs]);
#pragma unroll
            for (int n = 0; n < 4; ++n)
                b[n] = *(const bf16x8*)(&Bs[(wc + n * 16 + lr) * BK + cs]);
#pragma unroll
            for (int m = 0; m < 2; ++m)
#pragma unroll
                for (int n = 0; n < 4; ++n)
                    acc[m][n] = __builtin_amdgcn_mfma_f32_16x16x32_bf16(a[m], b[n], acc[m][n], 0, 0, 0);
        }
        __syncthreads();
    }

    // C/D frag: col=lane&15, row=(lane>>4)*4+j ; write EOT swizzled (K-dim = ec)
#pragma unroll
    for (int m = 0; m < 2; ++m) {
#pragma unroll
        for (int n = 0; n < 4; ++n) {
            const int col = bcol + wc + n * 16 + lr;     // C index
#pragma unroll
            for (int j = 0; j < 4; ++j) {
                const int row = brow + wr + m * 16 + lk * 4 + j;   // DOUT index
                const int ec = e * C_ + col;
                EOT[(size_t)row * (E_ * C_) + swz(row, ec)] =
                    (bf16_t)(acc[m][n][j] + expert_b[e * DOUT + row]);
            }
        }
    }
}

// ============ combine+residual GEMM: A direct-to-reg, B via LDS ============
// 128x128 block, 4 waves (2x2) of 64x64. A (f32: cw or xtail) is read
// per-wave straight from global into registers (no LDS round-trip); only
// B (bf16 pre-swizzled ws) is DMA-staged. Cuts LDS reads to 256 B/MFMA.
// z=0: out += w0 * sum_{ec<4096}  cw[s][ec]   * EOT[m][ec]
// z=1: out += w0 * sum_{ec>=4096} cw[s][ec]   * EOT[m][ec]
// z=2: out += w1 * (sum_d x[s][d] * RWT[m][d] + residual_b[m])
__global__ __launch_bounds__(256, 3)
void combine_gemm(const float* __restrict__ cw, const bf16_t* __restrict__ EOT,
                  const float* __restrict__ xtail, const bf16_t* __restrict__ RWT,
                  const float* __restrict__ residual_b, const float* __restrict__ rw,
                  float* __restrict__ out)
{
    __shared__ bf16_t Bs[BN * BK];   // 16 KB: EOT or RWT rows (DOUT)
    const int tid = threadIdx.x;

    // T1: bijective XCD-chunked swizzle. nwg = 768 -> 96 logical ids per XCD.
    int id = blockIdx.x + 8 * (blockIdx.y + 32 * blockIdx.z);
    id = (id & 7) * 96 + (id >> 3);
    const int bx = id & 7, by = (id >> 3) & 31, z = id >> 8;

    const int brow = by * BM;   // token
    const int bcol = bx * BN;   // DOUT

    const float* A;
    const bf16_t* B;
    int ld;
    if (z == 0)      { A = cw + (size_t)brow * 8192;        B = EOT + (size_t)bcol * 8192;        ld = 8192; }
    else if (z == 1) { A = cw + (size_t)brow * 8192 + 4096; B = EOT + (size_t)bcol * 8192 + 4096; ld = 8192; }
    else             { A = xtail + (size_t)brow * 4096;     B = RWT + (size_t)bcol * 4096;        ld = 4096; }

    const int w = tid >> 6, l = tid & 63;
    const int wr = (w >> 1) * 64, wc = (w & 1) * 64;   // wave tile 64x64
    const int lr = l & 15, lk = l >> 4, sw = (l & 7) << 3;

    // per-lane A base: row = brow-local wr + m*16 + lr ; col = k0 + kk*32 + lk*8
    const float* Alane = A + (size_t)(wr + lr) * ld + lk * 8;

    f32x4 acc[4][4] = {};

    for (int k0 = 0; k0 < 4096; k0 += BK) {
        // B: DMA into LDS (pre-swizzled source)
        stage_bf16<BN * BK, 4>(Bs, B + k0, ld, tid);
        // A: direct global -> regs (own fragments only), issued before the barrier
        f32x4 ar[4][2][2];
#pragma unroll
        for (int m = 0; m < 4; ++m) {
            const float* ap = Alane + (size_t)m * 16 * ld + k0;
#pragma unroll
            for (int kk = 0; kk < 2; ++kk) {
                ar[m][kk][0] = *(const f32x4*)(ap + kk * 32);
                ar[m][kk][1] = *(const f32x4*)(ap + kk * 32 + 4);
            }
        }
        __syncthreads();
#pragma unroll
        for (int kk = 0; kk < 2; ++kk) {
            const int cs = (kk * 32 + lk * 8) ^ sw;
            bf16x8 b[4];
#pragma unroll
            for (int n = 0; n < 4; ++n)
                b[n] = *(const bf16x8*)(&Bs[(wc + n * 16 + lr) * BK + cs]);
#pragma unroll
            for (int m = 0; m < 4; ++m) {
                bf16x8 a;
#pragma unroll
                for (int j = 0; j < 4; ++j) {
                    a[j]     = (bf16_t)ar[m][kk][0][j];
                    a[j + 4] = (bf16_t)ar[m][kk][1][j];
                }
#pragma unroll
                for (int n = 0; n < 4; ++n)
                    acc[m][n] = __builtin_amdgcn_mfma_f32_16x16x32_bf16(a, b[n], acc[m][n], 0, 0, 0);
            }
        }
        __syncthreads();
    }

#pragma unroll
    for (int m = 0; m < 4; ++m) {
#pragma unroll
        for (int n = 0; n < 4; ++n) {
            const int col = bcol + wc + n * 16 + lr;     // DOUT
#pragma unroll
            for (int j = 0; j < 4; ++j) {
                const int row = brow + wr + m * 16 + lk * 4 + j;   // token
                float v = acc[m][n][j];
                if (z == 2) v += residual_b[col];
                const float scale = rw[2 * row + (z == 2 ? 1 : 0)];
                atomicAdd(&out[(size_t)row * DOUT + col], scale * v);
            }
        }
    }
}

extern "C" void kernel_launch(void* const* d_in, const int* in_sizes, int n_in,
                              void* d_out, int out_size, void* d_ws, size_t ws_size,
                              hipStream_t stream)
{
    const float* inputs     = (const float*)d_in[0];
    const float* expert_w   = (const float*)d_in[1];
    const float* expert_b   = (const float*)d_in[2];
    const float* residual_w = (const float*)d_in[3];
    const float* residual_b = (const float*)d_in[4];
    const float* combine_w  = (const float*)d_in[5];
    const float* resid_wt   = (const float*)d_in[6];
    float* out = (float*)d_out;
    char* ws = (char*)d_ws;

    bf16_t* WT  = (bf16_t*)(ws + WS_WT);
    bf16_t* RWT = (bf16_t*)(ws + WS_RWT);
    bf16_t* EOT = (bf16_t*)(ws + WS_EOT);

    // 0) zero the output (blend accumulates atomically)
    hipMemsetAsync(d_out, 0, (size_t)out_size * sizeof(float), stream);

    // 1) weights -> bf16 transposed + swizzled
    transpose_cast_kernel<<<dim3(32, 128, 9), dim3(32, 8), 0, stream>>>(
        expert_w, residual_w, WT, RWT);

    // 2) expert GEMM -> EOT (bf16, swizzled, [DOUT][E*C])
    expert_gemm<<<dim3(C_ / BN, DOUT / BM, E_), NT, 0, stream>>>(
        WT, inputs, EOT, expert_b);

    // 3) fused combine (K split in 2) + residual, atomic blend into out
    combine_gemm<<<dim3(8, 32, 3), 256, 0, stream>>>(
        combine_w, EOT, inputs + (size_t)E_ * C_ * DIN, RWT,
        residual_b, resid_wt, out);
}

// Round 9
// 446.140 us; speedup vs baseline: 1.3019x; 1.3019x over previous
//
#include <hip/hip_runtime.h>
#include <hip/hip_bf16.h>

typedef __bf16 bf16_t;
typedef __bf16 bf16x8 __attribute__((ext_vector_type(8)));
typedef float f32x4 __attribute__((ext_vector_type(4)));

#define DEVI static __device__ __forceinline__

static constexpr int E_ = 8, C_ = 1024, DIN = 4096, DOUT = 1024, TOK = 4096;
static constexpr int EC = 8192;
static constexpr int BM = 128, BN = 128, BK = 64;
static constexpr int NT = 512;                 // expert: 8 waves / block (R3 champion)

// ---- workspace layout (bytes) ----  total 120 MiB
// WT is dead after expert_gemm; CWf (64 MiB) overwrites it.
static constexpr size_t WS_WT  = 0;                          // [E][DOUT][DIN] bf16 (swizzled) -> later CWf
static constexpr size_t WS_CWF = 0;                          // [TOK/16][EC/32][64][8] bf16 frag-major
static constexpr size_t WS_RWT = (size_t)64 << 20;           // [DOUT][DIN] bf16 (swizzled)
static constexpr size_t WS_EOT = WS_RWT + ((size_t)8 << 20); // [DOUT][EC] bf16 (swizzled)
static constexpr size_t WS_XF  = WS_EOT + ((size_t)16 << 20);// [TOK/16][DIN/32][64][8] bf16 frag-major

// XOR-swizzle within each 64-element K-group: chunk(col>>3 & 7) ^= row&7.
DEVI int swz(int row, int col) {
    return (col & ~63) | ((col & 56) ^ ((row & 7) << 3)) | (col & 7);
}

// ============ prepass: transpose + cast weights to bf16 [out][in], swizzled ============
__global__ __launch_bounds__(256)
void transpose_cast_kernel(const float* __restrict__ expert_w,
                           const float* __restrict__ residual_w,
                           bf16_t* __restrict__ wt, bf16_t* __restrict__ rwt)
{
    __shared__ float tile[32][33];
    const int z = blockIdx.z;
    const float* src;
    bf16_t* dst;
    if (z < 8) { src = expert_w + (size_t)z * DIN * DOUT; dst = wt + (size_t)z * DOUT * DIN; }
    else       { src = residual_w;                         dst = rwt; }
    const int c0 = blockIdx.x * 32;   // col in src  (DOUT dim -> dst row)
    const int r0 = blockIdx.y * 32;   // row in src  (DIN dim  -> dst col/K)
    const int tx = threadIdx.x, ty = threadIdx.y;  // 32 x 8
#pragma unroll
    for (int k = 0; k < 4; ++k)
        tile[ty + 8 * k][tx] = src[(size_t)(r0 + ty + 8 * k) * DOUT + c0 + tx];
    __syncthreads();
#pragma unroll
    for (int k = 0; k < 4; ++k) {
        const int row = c0 + ty + 8 * k;      // DOUT
        const int col = r0 + tx;              // DIN (K)
        dst[(size_t)row * DIN + swz(row, col)] = (bf16_t)tile[tx][ty + 8 * k];
    }
}

// ============ prepass: cast f32 [rows][ldin] -> bf16 A-frag-major [st][kt][lane][8] ============
// A-frag (16x16x32 MFMA): lane l holds A[m = l&15][k = (l>>4)*8 + j].
__global__ __launch_bounds__(256)
void cast_frag_kernel(const float* __restrict__ in, bf16_t* __restrict__ outf,
                      int ldin, int ktlog)
{
    const size_t gid = (size_t)blockIdx.x * 256 + threadIdx.x;   // tile*64 + lane
    const int lane = (int)(gid & 63);
    const size_t tile = gid >> 6;
    const size_t st = tile >> ktlog;
    const size_t kt = tile & (((size_t)1 << ktlog) - 1);
    const float* p = in + (st * 16 + (lane & 15)) * (size_t)ldin + kt * 32 + (lane >> 4) * 8;
    f32x4 v0 = *(const f32x4*)p;
    f32x4 v1 = *(const f32x4*)(p + 4);
    bf16x8 h;
    h[0] = (bf16_t)v0[0]; h[1] = (bf16_t)v0[1];
    h[2] = (bf16_t)v0[2]; h[3] = (bf16_t)v0[3];
    h[4] = (bf16_t)v1[0]; h[5] = (bf16_t)v1[1];
    h[6] = (bf16_t)v1[2]; h[7] = (bf16_t)v1[3];
    *(bf16x8*)(outf + gid * 8) = h;
}

// ============ LDS staging ============
// bf16 ws operand, pre-swizzled source: linear DMA copy. NW = waves/block.
template<int NELEM, int NW>
DEVI void stage_bf16(bf16_t* lds, const bf16_t* g, int ld, int tid)
{
    constexpr int PER_WAVE = NELEM / NW;
    constexpr int NI = PER_WAVE / 512;
    const int w = tid >> 6, l = tid & 63;
#pragma unroll
    for (int i = 0; i < NI; ++i) {
        const int eoff = w * PER_WAVE + i * 512 + l * 8;
        const int r = eoff >> 6, c = eoff & 63;
        const bf16_t* gp = g + (size_t)r * ld + c;
        bf16_t* lp = lds + w * PER_WAVE + i * 512;   // wave-uniform base; HW adds lane*16B
        __builtin_amdgcn_global_load_lds(
            (const __attribute__((address_space(1))) void*)gp,
            (__attribute__((address_space(3))) void*)lp, 16, 0, 0);
    }
}

// f32 operand: reg-stage + cvt + swizzled ds_write (expert kernel, 8 waves)
template<int NELEM>
DEVI void stage_f32(bf16_t* lds, const float* __restrict__ g, int ld, int tid)
{
    constexpr int NI = NELEM / (NT * 8);
#pragma unroll
    for (int i = 0; i < NI; ++i) {
        const int eoff = i * NT * 8 + tid * 8;
        const int r = eoff >> 6, c = eoff & 63;        // c is 8-aligned
        const float* gp = g + (size_t)r * ld + c;
        f32x4 v0 = *(const f32x4*)(gp);
        f32x4 v1 = *(const f32x4*)(gp + 4);
        bf16x8 h;
        h[0] = (bf16_t)v0[0]; h[1] = (bf16_t)v0[1];
        h[2] = (bf16_t)v0[2]; h[3] = (bf16_t)v0[3];
        h[4] = (bf16_t)v1[0]; h[5] = (bf16_t)v1[1];
        h[6] = (bf16_t)v1[2]; h[7] = (bf16_t)v1[3];
        const int cs = (c & 56) ^ ((r & 7) << 3);
        *(bf16x8*)(lds + r * 64 + cs) = h;
    }
}

// ============ expert GEMM: EOT[m][e*C+c] = sum_d WT_e[m][d]*front_e[c][d] + b ============
// (unchanged R3 champion)
__global__ __launch_bounds__(NT, 4)
void expert_gemm(const bf16_t* __restrict__ WT, const float* __restrict__ inputs,
                 bf16_t* __restrict__ EOT, const float* __restrict__ expert_b)
{
    __shared__ bf16_t As[BM * BK];
    __shared__ bf16_t Bs[BN * BK];
    const int tid = threadIdx.x;

    // T1: bijective XCD-chunked swizzle. nwg = 512 -> chunk k = expert k.
    int id = blockIdx.x + 8 * (blockIdx.y + 8 * blockIdx.z);
    id = (id & 7) * 64 + (id >> 3);
    const int bx = id & 7, by = (id >> 3) & 7, e = id >> 6;

    const int brow = by * BM;   // DOUT
    const int bcol = bx * BN;   // C
    const bf16_t* A = WT + (size_t)e * DOUT * DIN + (size_t)brow * DIN;
    const float*  B = inputs + (size_t)e * C_ * DIN + (size_t)bcol * DIN;

    const int w = tid >> 6, l = tid & 63;
    const int wr = (w >> 1) * 32, wc = (w & 1) * 64;   // wave tile 32x64
    const int lr = l & 15, lk = l >> 4, sw = (l & 7) << 3;

    f32x4 acc[2][4] = {};

    for (int k0 = 0; k0 < DIN; k0 += BK) {
        stage_bf16<BM * BK, 8>(As, A + k0, DIN, tid);
        stage_f32<BN * BK>(Bs, B + k0, DIN, tid);
        __syncthreads();
#pragma unroll
        for (int kk = 0; kk < 2; ++kk) {
            const int cs = (kk * 32 + lk * 8) ^ sw;
            bf16x8 a[2], b[4];
#pragma unroll
            for (int m = 0; m < 2; ++m)
                a[m] = *(const bf16x8*)(&As[(wr + m * 16 + lr) * BK + cs]);
#pragma unroll
            for (int n = 0; n < 4; ++n)
                b[n] = *(const bf16x8*)(&Bs[(wc + n * 16 + lr) * BK + cs]);
#pragma unroll
            for (int m = 0; m < 2; ++m)
#pragma unroll
                for (int n = 0; n < 4; ++n)
                    acc[m][n] = __builtin_amdgcn_mfma_f32_16x16x32_bf16(a[m], b[n], acc[m][n], 0, 0, 0);
        }
        __syncthreads();
    }

    // C/D frag: col=lane&15, row=(lane>>4)*4+j ; write EOT swizzled (K-dim = ec)
#pragma unroll
    for (int m = 0; m < 2; ++m) {
#pragma unroll
        for (int n = 0; n < 4; ++n) {
            const int col = bcol + wc + n * 16 + lr;     // C index
#pragma unroll
            for (int j = 0; j < 4; ++j) {
                const int row = brow + wr + m * 16 + lk * 4 + j;   // DOUT index
                const int ec = e * C_ + col;
                EOT[(size_t)row * EC + swz(row, ec)] =
                    (bf16_t)(acc[m][n][j] + expert_b[e * DOUT + row]);
            }
        }
    }
}

// ============ combine+residual GEMM: A frag-major direct-to-reg (prefetched),
// B via double-buffered global_load_lds, counted vmcnt, raw barriers ============
// z=0: out += w0 * sum_{ec<4096}  cw[s][ec]   * EOT[m][ec]
// z=1: out += w0 * sum_{ec>=4096} cw[s][ec]   * EOT[m][ec]
// z=2: out += w1 * (sum_d x[s][d] * RWT[m][d] + residual_b[m])
__global__ __launch_bounds__(256, 3)
void combine_gemm(const bf16_t* __restrict__ CWf, const bf16_t* __restrict__ Xf,
                  const bf16_t* __restrict__ EOT, const bf16_t* __restrict__ RWT,
                  const float* __restrict__ residual_b, const float* __restrict__ rw,
                  float* __restrict__ out)
{
    __shared__ bf16_t Bs0[BN * BK];   // 16 KB
    __shared__ bf16_t Bs1[BN * BK];   // 16 KB
    const int tid = threadIdx.x;

    // T1: bijective XCD-chunked swizzle. nwg = 768 -> 96 logical ids per XCD.
    int id = blockIdx.x;
    id = (id & 7) * 96 + (id >> 3);
    const int bx = id & 7, by = (id >> 3) & 31, z = id >> 8;

    const int brow = by * BM;   // token
    const int bcol = bx * BN;   // DOUT

    const bf16_t* B; int ldB;
    const bf16_t* Af; int ktoff, ktlog;
    if (z < 2) { B = EOT + (size_t)bcol * EC + z * 4096; ldB = EC;  Af = CWf; ktoff = z * 128; ktlog = 8; }
    else       { B = RWT + (size_t)bcol * DIN;           ldB = DIN; Af = Xf;  ktoff = 0;       ktlog = 7; }

    const int w = tid >> 6, l = tid & 63;
    const int wr = (w >> 1) * 64, wc = (w & 1) * 64;   // 2x2 waves of 64x64
    const int lr = l & 15, lk = l >> 4, sw = (l & 7) << 3;

    // A-frag lane pointers: Af + ((st*KT + kt)*64 + l)*8 ; kt step = 512 elems
    const int st0 = (brow + wr) >> 4;
    const bf16_t* aP[4];
#pragma unroll
    for (int m = 0; m < 4; ++m)
        aP[m] = Af + ((size_t)((st0 + m) << ktlog) + ktoff) * 512 + l * 8;

    f32x4 acc[4][4] = {};
    bf16x8 A0[4][2], A1[4][2];

#define ALOAD(AR, T) { _Pragma("unroll") for (int m_ = 0; m_ < 4; ++m_) { \
      const bf16_t* ap_ = aP[m_] + (size_t)(2 * (T)) * 512; \
      AR[m_][0] = *(const bf16x8*)(ap_); AR[m_][1] = *(const bf16x8*)(ap_ + 512); } }

#define STAGE(LDS, K0) stage_bf16<BN * BK, 4>(LDS, B + (K0), ldB, tid)

#define MFMAS(AR, BSP) { _Pragma("unroll") for (int kk_ = 0; kk_ < 2; ++kk_) { \
      const int cs_ = (kk_ * 32 + lk * 8) ^ sw; bf16x8 bfr_[4]; \
      _Pragma("unroll") for (int n_ = 0; n_ < 4; ++n_) \
        bfr_[n_] = *(const bf16x8*)(&(BSP)[(wc + n_ * 16 + lr) * BK + cs_]); \
      _Pragma("unroll") for (int m_ = 0; m_ < 4; ++m_) \
        _Pragma("unroll") for (int n_ = 0; n_ < 4; ++n_) \
          acc[m_][n_] = __builtin_amdgcn_mfma_f32_16x16x32_bf16(AR[m_][kk_], bfr_[n_], acc[m_][n_], 0, 0, 0); } }

#define SBAR { __builtin_amdgcn_sched_barrier(0); __builtin_amdgcn_s_barrier(); \
               __builtin_amdgcn_sched_barrier(0); }
#define WAITP { asm volatile("s_waitcnt vmcnt(12)" ::: "memory"); __builtin_amdgcn_sched_barrier(0); }
#define WAIT0 { asm volatile("s_waitcnt vmcnt(0)"  ::: "memory"); __builtin_amdgcn_sched_barrier(0); }

    // prologue: stage iter 0
    STAGE(Bs0, 0);
    ALOAD(A0, 0);

    // main loop: 64 K-steps, unrolled x2 (static A0/A1), iters 0..61 here
    for (int t = 0; t < 62; t += 2) {
        SBAR;                            // all waves done reading Bs1 (iter t-1)
        STAGE(Bs1, (t + 1) * BK);        // DMA next tile (4 instrs/wave)
        ALOAD(A1, t + 1);                // prefetch A regs (8 instrs)
        WAITP;                           // drain iter-t loads, keep 12 newest in flight
        SBAR;                            // all waves' DMA(t) landed
        MFMAS(A0, Bs0);
        SBAR;                            // all waves done reading Bs0
        STAGE(Bs0, (t + 2) * BK);
        ALOAD(A0, t + 2);
        WAITP;
        SBAR;
        MFMAS(A1, Bs1);
    }
    // tail: iters 62, 63
    SBAR;
    STAGE(Bs1, 63 * BK);
    ALOAD(A1, 63);
    WAITP;
    SBAR;
    MFMAS(A0, Bs0);
    SBAR;
    WAIT0;
    SBAR;
    MFMAS(A1, Bs1);

#undef ALOAD
#undef STAGE
#undef MFMAS
#undef SBAR
#undef WAITP
#undef WAIT0

    // epilogue: C/D frag col=lane&15, row=(lane>>4)*4+j ; atomic blend
#pragma unroll
    for (int m = 0; m < 4; ++m) {
#pragma unroll
        for (int n = 0; n < 4; ++n) {
            const int col = bcol + wc + n * 16 + lr;     // DOUT
#pragma unroll
            for (int j = 0; j < 4; ++j) {
                const int row = brow + wr + m * 16 + lk * 4 + j;   // token
                float v = acc[m][n][j];
                if (z == 2) v += residual_b[col];
                const float scale = rw[2 * row + (z == 2 ? 1 : 0)];
                atomicAdd(&out[(size_t)row * DOUT + col], scale * v);
            }
        }
    }
}

extern "C" void kernel_launch(void* const* d_in, const int* in_sizes, int n_in,
                              void* d_out, int out_size, void* d_ws, size_t ws_size,
                              hipStream_t stream)
{
    const float* inputs     = (const float*)d_in[0];
    const float* expert_w   = (const float*)d_in[1];
    const float* expert_b   = (const float*)d_in[2];
    const float* residual_w = (const float*)d_in[3];
    const float* residual_b = (const float*)d_in[4];
    const float* combine_w  = (const float*)d_in[5];
    const float* resid_wt   = (const float*)d_in[6];
    float* out = (float*)d_out;
    char* ws = (char*)d_ws;

    bf16_t* WT  = (bf16_t*)(ws + WS_WT);
    bf16_t* CWf = (bf16_t*)(ws + WS_CWF);   // overlaps WT (WT dead after expert)
    bf16_t* RWT = (bf16_t*)(ws + WS_RWT);
    bf16_t* EOT = (bf16_t*)(ws + WS_EOT);
    bf16_t* Xf  = (bf16_t*)(ws + WS_XF);

    // 0) zero the output (blend accumulates atomically)
    hipMemsetAsync(d_out, 0, (size_t)out_size * sizeof(float), stream);

    // 1) weights -> bf16 transposed + swizzled
    transpose_cast_kernel<<<dim3(32, 128, 9), dim3(32, 8), 0, stream>>>(
        expert_w, residual_w, WT, RWT);

    // 2) expert GEMM -> EOT (bf16, swizzled, [DOUT][EC])   (uses WT)
    expert_gemm<<<dim3(C_ / BN, DOUT / BM, E_), NT, 0, stream>>>(
        WT, inputs, EOT, expert_b);

    // 3) cast combine_weights / xtail -> bf16 A-frag-major (CWf overwrites WT)
    cast_frag_kernel<<<dim3((TOK / 16) * (EC / 32) / 4), 256, 0, stream>>>(
        combine_w, CWf, EC, 8);
    cast_frag_kernel<<<dim3((TOK / 16) * (DIN / 32) / 4), 256, 0, stream>>>(
        inputs + (size_t)E_ * C_ * DIN, Xf, DIN, 7);

    // 4) fused combine (K split in 2) + residual, atomic blend into out
    combine_gemm<<<dim3(768), 256, 0, stream>>>(
        CWf, Xf, EOT, RWT, residual_b, resid_wt, out);
}

// Round 10
// 397.193 us; speedup vs baseline: 1.4623x; 1.1232x over previous
//
#include <hip/hip_runtime.h>
#include <hip/hip_bf16.h>

typedef __bf16 bf16_t;
typedef __bf16 bf16x8 __attribute__((ext_vector_type(8)));
typedef float f32x4 __attribute__((ext_vector_type(4)));

#define DEVI static __device__ __forceinline__

static constexpr int E_ = 8, C_ = 1024, DIN = 4096, DOUT = 1024, TOK = 4096;
static constexpr int EC = 8192;
static constexpr int BM = 128, BN = 128, BK = 64;
static constexpr int NT = 512;                 // 8 waves / block (R3 champion)

// ---- workspace layout (bytes) ----  peak 120 MiB (R8-proven footprint)
// WT (64 MiB) is dead after expert_gemm; CWB overwrites it.
static constexpr size_t WS_WT  = 0;                           // [E][DOUT][DIN] bf16 swizzled -> later CWB
static constexpr size_t WS_CWB = 0;                           // [TOK][EC] bf16 swizzled
static constexpr size_t WS_RWT = (size_t)64 << 20;            // [DOUT][DIN] bf16 swizzled
static constexpr size_t WS_EOT = WS_RWT + ((size_t)8 << 20);  // [DOUT][EC] bf16 swizzled
static constexpr size_t WS_XB  = WS_EOT + ((size_t)16 << 20); // [TOK][DIN] bf16 swizzled

// XOR-swizzle within each 64-element K-group: chunk(col>>3 & 7) ^= row&7.
// Pre-applied to the GLOBAL layout of all bf16 ws operands (rule 21).
DEVI int swz(int row, int col) {
    return (col & ~63) | ((col & 56) ^ ((row & 7) << 3)) | (col & 7);
}

// ============ prepass: transpose + cast weights to bf16 [out][in], swizzled ============
__global__ __launch_bounds__(256)
void transpose_cast_kernel(const float* __restrict__ expert_w,
                           const float* __restrict__ residual_w,
                           bf16_t* __restrict__ wt, bf16_t* __restrict__ rwt)
{
    __shared__ float tile[32][33];
    const int z = blockIdx.z;
    const float* src;
    bf16_t* dst;
    if (z < 8) { src = expert_w + (size_t)z * DIN * DOUT; dst = wt + (size_t)z * DOUT * DIN; }
    else       { src = residual_w;                         dst = rwt; }
    const int c0 = blockIdx.x * 32;   // col in src  (DOUT dim -> dst row)
    const int r0 = blockIdx.y * 32;   // row in src  (DIN dim  -> dst col/K)
    const int tx = threadIdx.x, ty = threadIdx.y;  // 32 x 8
#pragma unroll
    for (int k = 0; k < 4; ++k)
        tile[ty + 8 * k][tx] = src[(size_t)(r0 + ty + 8 * k) * DOUT + c0 + tx];
    __syncthreads();
#pragma unroll
    for (int k = 0; k < 4; ++k) {
        const int row = c0 + ty + 8 * k;      // DOUT
        const int col = r0 + tx;              // DIN (K)
        dst[(size_t)row * DIN + swz(row, col)] = (bf16_t)tile[tx][ty + 8 * k];
    }
}

// ============ prepass: cast f32 row-major -> bf16 row-major, swizzled ============
// Thread owns one (row, 64-col group); chunk i goes to chunk i^(row&7).
// Same pattern as R7's merge_swz (proven). grpslog = log2(ld/64).
__global__ __launch_bounds__(256)
void cast_swz_kernel(const float* __restrict__ in, bf16_t* __restrict__ outb,
                     int ld, int grpslog)
{
    const size_t gid = (size_t)blockIdx.x * 256 + threadIdx.x;
    const size_t row = gid >> grpslog;
    const int grp = (int)(gid & ((1u << grpslog) - 1));
    const float* p = in + row * (size_t)ld + grp * 64;
    bf16_t* q = outb + row * (size_t)ld + grp * 64;
    const int key = (int)(row & 7);
#pragma unroll
    for (int i = 0; i < 8; ++i) {
        f32x4 v0 = *(const f32x4*)(p + i * 8);
        f32x4 v1 = *(const f32x4*)(p + i * 8 + 4);
        bf16x8 h;
        h[0] = (bf16_t)v0[0]; h[1] = (bf16_t)v0[1];
        h[2] = (bf16_t)v0[2]; h[3] = (bf16_t)v0[3];
        h[4] = (bf16_t)v1[0]; h[5] = (bf16_t)v1[1];
        h[6] = (bf16_t)v1[2]; h[7] = (bf16_t)v1[3];
        *(bf16x8*)(q + 8 * (i ^ key)) = h;
    }
}

// ============ LDS staging ============
// bf16 ws operand, pre-swizzled source: linear DMA copy (8 waves)
template<int NELEM>
DEVI void stage_bf16(bf16_t* lds, const bf16_t* g, int ld, int tid)
{
    constexpr int PER_WAVE = NELEM / 8;
    constexpr int NI = PER_WAVE / 512;
    const int w = tid >> 6, l = tid & 63;
#pragma unroll
    for (int i = 0; i < NI; ++i) {
        const int eoff = w * PER_WAVE + i * 512 + l * 8;
        const int r = eoff >> 6, c = eoff & 63;
        const bf16_t* gp = g + (size_t)r * ld + c;
        bf16_t* lp = lds + w * PER_WAVE + i * 512;   // wave-uniform base; HW adds lane*16B
        __builtin_amdgcn_global_load_lds(
            (const __attribute__((address_space(1))) void*)gp,
            (__attribute__((address_space(3))) void*)lp, 16, 0, 0);
    }
}

// f32 operand: reg-stage + cvt + swizzled ds_write (expert kernel only)
template<int NELEM>
DEVI void stage_f32(bf16_t* lds, const float* __restrict__ g, int ld, int tid)
{
    constexpr int NI = NELEM / (NT * 8);
#pragma unroll
    for (int i = 0; i < NI; ++i) {
        const int eoff = i * NT * 8 + tid * 8;
        const int r = eoff >> 6, c = eoff & 63;        // c is 8-aligned
        const float* gp = g + (size_t)r * ld + c;
        f32x4 v0 = *(const f32x4*)(gp);
        f32x4 v1 = *(const f32x4*)(gp + 4);
        bf16x8 h;
        h[0] = (bf16_t)v0[0]; h[1] = (bf16_t)v0[1];
        h[2] = (bf16_t)v0[2]; h[3] = (bf16_t)v0[3];
        h[4] = (bf16_t)v1[0]; h[5] = (bf16_t)v1[1];
        h[6] = (bf16_t)v1[2]; h[7] = (bf16_t)v1[3];
        const int cs = (c & 56) ^ ((r & 7) << 3);
        *(bf16x8*)(lds + r * 64 + cs) = h;
    }
}

// ============ expert GEMM: EOT[m][e*C+c] = sum_d WT_e[m][d]*front_e[c][d] + b ============
// (unchanged R3 champion)
__global__ __launch_bounds__(NT, 4)
void expert_gemm(const bf16_t* __restrict__ WT, const float* __restrict__ inputs,
                 bf16_t* __restrict__ EOT, const float* __restrict__ expert_b)
{
    __shared__ bf16_t As[BM * BK];
    __shared__ bf16_t Bs[BN * BK];
    const int tid = threadIdx.x;

    // T1: bijective XCD-chunked swizzle. nwg = 512 -> chunk k = expert k.
    int id = blockIdx.x + 8 * (blockIdx.y + 8 * blockIdx.z);
    id = (id & 7) * 64 + (id >> 3);
    const int bx = id & 7, by = (id >> 3) & 7, e = id >> 6;

    const int brow = by * BM;   // DOUT
    const int bcol = bx * BN;   // C
    const bf16_t* A = WT + (size_t)e * DOUT * DIN + (size_t)brow * DIN;
    const float*  B = inputs + (size_t)e * C_ * DIN + (size_t)bcol * DIN;

    const int w = tid >> 6, l = tid & 63;
    const int wr = (w >> 1) * 32, wc = (w & 1) * 64;   // wave tile 32x64
    const int lr = l & 15, lk = l >> 4, sw = (l & 7) << 3;

    f32x4 acc[2][4] = {};

    for (int k0 = 0; k0 < DIN; k0 += BK) {
        stage_bf16<BM * BK>(As, A + k0, DIN, tid);
        stage_f32<BN * BK>(Bs, B + k0, DIN, tid);
        __syncthreads();
#pragma unroll
        for (int kk = 0; kk < 2; ++kk) {
            const int cs = (kk * 32 + lk * 8) ^ sw;
            bf16x8 a[2], b[4];
#pragma unroll
            for (int m = 0; m < 2; ++m)
                a[m] = *(const bf16x8*)(&As[(wr + m * 16 + lr) * BK + cs]);
#pragma unroll
            for (int n = 0; n < 4; ++n)
                b[n] = *(const bf16x8*)(&Bs[(wc + n * 16 + lr) * BK + cs]);
#pragma unroll
            for (int m = 0; m < 2; ++m)
#pragma unroll
                for (int n = 0; n < 4; ++n)
                    acc[m][n] = __builtin_amdgcn_mfma_f32_16x16x32_bf16(a[m], b[n], acc[m][n], 0, 0, 0);
        }
        __syncthreads();
    }

    // C/D frag: col=lane&15, row=(lane>>4)*4+j ; write EOT swizzled (K-dim = ec)
#pragma unroll
    for (int m = 0; m < 2; ++m) {
#pragma unroll
        for (int n = 0; n < 4; ++n) {
            const int col = bcol + wc + n * 16 + lr;     // C index
#pragma unroll
            for (int j = 0; j < 4; ++j) {
                const int row = brow + wr + m * 16 + lk * 4 + j;   // DOUT index
                const int ec = e * C_ + col;
                EOT[(size_t)row * EC + swz(row, ec)] =
                    (bf16_t)(acc[m][n][j] + expert_b[e * DOUT + row]);
            }
        }
    }
}

// ============ fused combine+residual GEMM, z-split K, atomic blend ============
// Both operands bf16 pre-swizzled in ws -> both staged via global_load_lds.
// z=0: out += w0 * sum_{ec<4096}  cw[s][ec]   * EOT[m][ec]
// z=1: out += w0 * sum_{ec>=4096} cw[s][ec]   * EOT[m][ec]
// z=2: out += w1 * (sum_d x[s][d] * RWT[m][d] + residual_b[m])
__global__ __launch_bounds__(NT, 4)
void combine_gemm(const bf16_t* __restrict__ CWB, const bf16_t* __restrict__ EOT,
                  const bf16_t* __restrict__ XB, const bf16_t* __restrict__ RWT,
                  const float* __restrict__ residual_b, const float* __restrict__ rw,
                  float* __restrict__ out)
{
    __shared__ bf16_t As[BM * BK];   // cw or x rows (tokens)
    __shared__ bf16_t Bs[BN * BK];   // EOT or RWT rows (DOUT)
    const int tid = threadIdx.x;

    // T1: bijective XCD-chunked swizzle. nwg = 768 -> 96 logical ids per XCD.
    int id = blockIdx.x + 8 * (blockIdx.y + 32 * blockIdx.z);
    id = (id & 7) * 96 + (id >> 3);
    const int bx = id & 7, by = (id >> 3) & 31, z = id >> 8;

    const int brow = by * BM;   // token
    const int bcol = bx * BN;   // DOUT

    const bf16_t* A;
    const bf16_t* B;
    int ld;
    if (z == 0)      { A = CWB + (size_t)brow * EC;        B = EOT + (size_t)bcol * EC;        ld = EC; }
    else if (z == 1) { A = CWB + (size_t)brow * EC + 4096; B = EOT + (size_t)bcol * EC + 4096; ld = EC; }
    else             { A = XB + (size_t)brow * DIN;        B = RWT + (size_t)bcol * DIN;       ld = DIN; }

    const int w = tid >> 6, l = tid & 63;
    const int wr = (w >> 1) * 32, wc = (w & 1) * 64;   // wave tile 32x64
    const int lr = l & 15, lk = l >> 4, sw = (l & 7) << 3;

    f32x4 acc[2][4] = {};

    for (int k0 = 0; k0 < 4096; k0 += BK) {
        stage_bf16<BM * BK>(As, A + k0, ld, tid);
        stage_bf16<BN * BK>(Bs, B + k0, ld, tid);
        __syncthreads();
#pragma unroll
        for (int kk = 0; kk < 2; ++kk) {
            const int cs = (kk * 32 + lk * 8) ^ sw;
            bf16x8 a[2], b[4];
#pragma unroll
            for (int m = 0; m < 2; ++m)
                a[m] = *(const bf16x8*)(&As[(wr + m * 16 + lr) * BK + cs]);
#pragma unroll
            for (int n = 0; n < 4; ++n)
                b[n] = *(const bf16x8*)(&Bs[(wc + n * 16 + lr) * BK + cs]);
#pragma unroll
            for (int m = 0; m < 2; ++m)
#pragma unroll
                for (int n = 0; n < 4; ++n)
                    acc[m][n] = __builtin_amdgcn_mfma_f32_16x16x32_bf16(a[m], b[n], acc[m][n], 0, 0, 0);
        }
        __syncthreads();
    }

#pragma unroll
    for (int m = 0; m < 2; ++m) {
#pragma unroll
        for (int n = 0; n < 4; ++n) {
            const int col = bcol + wc + n * 16 + lr;     // DOUT
#pragma unroll
            for (int j = 0; j < 4; ++j) {
                const int row = brow + wr + m * 16 + lk * 4 + j;   // token
                float v = acc[m][n][j];
                if (z == 2) v += residual_b[col];
                const float scale = rw[2 * row + (z == 2 ? 1 : 0)];
                atomicAdd(&out[(size_t)row * DOUT + col], scale * v);
            }
        }
    }
}

extern "C" void kernel_launch(void* const* d_in, const int* in_sizes, int n_in,
                              void* d_out, int out_size, void* d_ws, size_t ws_size,
                              hipStream_t stream)
{
    const float* inputs     = (const float*)d_in[0];
    const float* expert_w   = (const float*)d_in[1];
    const float* expert_b   = (const float*)d_in[2];
    const float* residual_w = (const float*)d_in[3];
    const float* residual_b = (const float*)d_in[4];
    const float* combine_w  = (const float*)d_in[5];
    const float* resid_wt   = (const float*)d_in[6];
    float* out = (float*)d_out;
    char* ws = (char*)d_ws;

    bf16_t* WT  = (bf16_t*)(ws + WS_WT);
    bf16_t* CWB = (bf16_t*)(ws + WS_CWB);   // overwrites WT after expert
    bf16_t* RWT = (bf16_t*)(ws + WS_RWT);
    bf16_t* EOT = (bf16_t*)(ws + WS_EOT);
    bf16_t* XB  = (bf16_t*)(ws + WS_XB);

    // 0) zero the output (blend accumulates atomically)
    hipMemsetAsync(d_out, 0, (size_t)out_size * sizeof(float), stream);

    // 1) weights -> bf16 transposed + swizzled
    transpose_cast_kernel<<<dim3(32, 128, 9), dim3(32, 8), 0, stream>>>(
        expert_w, residual_w, WT, RWT);

    // 2) expert GEMM -> EOT (bf16, swizzled, [DOUT][EC])   (uses WT)
    expert_gemm<<<dim3(C_ / BN, DOUT / BM, E_), NT, 0, stream>>>(
        WT, inputs, EOT, expert_b);

    // 3) cast cw -> CWB (overwrites dead WT) and xtail -> XB, both swizzled bf16
    cast_swz_kernel<<<dim3((size_t)TOK * EC / 64 / 256), 256, 0, stream>>>(
        combine_w, CWB, EC, 7);
    cast_swz_kernel<<<dim3((size_t)TOK * DIN / 64 / 256), 256, 0, stream>>>(
        inputs + (size_t)E_ * C_ * DIN, XB, DIN, 6);

    // 4) fused combine (K split in 2) + residual, atomic blend into out
    combine_gemm<<<dim3(DOUT / BN, TOK / BM, 3), NT, 0, stream>>>(
        CWB, EOT, XB, RWT, residual_b, resid_wt, out);
}

// Round 11
// 392.540 us; speedup vs baseline: 1.4796x; 1.0119x over previous
//
#include <hip/hip_runtime.h>
#include <hip/hip_bf16.h>

typedef __bf16 bf16_t;
typedef __bf16 bf16x8 __attribute__((ext_vector_type(8)));
typedef float f32x4 __attribute__((ext_vector_type(4)));

#define DEVI static __device__ __forceinline__

static constexpr int E_ = 8, C_ = 1024, DIN = 4096, DOUT = 1024, TOK = 4096;
static constexpr int EC = 8192;
static constexpr int BM = 128, BN = 128, BK = 64;
static constexpr int NT = 512;                 // 8 waves / block, 32x64 per wave (R3 champion)

// ---- workspace layout (bytes) ----  (R3 layout, ~104 MiB)
static constexpr size_t WS_WT  = 0;                                      // [E][DOUT][DIN] bf16 (swizzled)
static constexpr size_t WS_RWT = WS_WT  + (size_t)E_ * DOUT * DIN * 2;   // [DOUT][DIN] bf16 (swizzled)
static constexpr size_t WS_EOT = WS_RWT + (size_t)DOUT * DIN * 2;        // [DOUT][EC] bf16 (swizzled)

// XOR-swizzle within each 64-element K-group: chunk(col>>3 & 7) ^= row&7.
// Pre-applied to the GLOBAL layout of bf16 ws operands (rule 21).
DEVI int swz(int row, int col) {
    return (col & ~63) | ((col & 56) ^ ((row & 7) << 3)) | (col & 7);
}

// ============ prepass: transpose + cast weights to bf16 [out][in], swizzled ============
__global__ __launch_bounds__(256)
void transpose_cast_kernel(const float* __restrict__ expert_w,
                           const float* __restrict__ residual_w,
                           bf16_t* __restrict__ wt, bf16_t* __restrict__ rwt)
{
    __shared__ float tile[32][33];
    const int z = blockIdx.z;
    const float* src;
    bf16_t* dst;
    if (z < 8) { src = expert_w + (size_t)z * DIN * DOUT; dst = wt + (size_t)z * DOUT * DIN; }
    else       { src = residual_w;                         dst = rwt; }
    const int c0 = blockIdx.x * 32;   // col in src  (DOUT dim -> dst row)
    const int r0 = blockIdx.y * 32;   // row in src  (DIN dim  -> dst col/K)
    const int tx = threadIdx.x, ty = threadIdx.y;  // 32 x 8
#pragma unroll
    for (int k = 0; k < 4; ++k)
        tile[ty + 8 * k][tx] = src[(size_t)(r0 + ty + 8 * k) * DOUT + c0 + tx];
    __syncthreads();
#pragma unroll
    for (int k = 0; k < 4; ++k) {
        const int row = c0 + ty + 8 * k;      // DOUT
        const int col = r0 + tx;              // DIN (K)
        dst[(size_t)row * DIN + swz(row, col)] = (bf16_t)tile[tx][ty + 8 * k];
    }
}

// ============ staging helpers (8 waves) ============
// bf16 ws operand, pre-swizzled source: linear DMA issue (no wait)
template<int NELEM>
DEVI void stage_bf16(bf16_t* lds, const bf16_t* g, int ld, int tid)
{
    constexpr int PER_WAVE = NELEM / 8;
    constexpr int NI = PER_WAVE / 512;
    const int w = tid >> 6, l = tid & 63;
#pragma unroll
    for (int i = 0; i < NI; ++i) {
        const int eoff = w * PER_WAVE + i * 512 + l * 8;
        const int r = eoff >> 6, c = eoff & 63;
        const bf16_t* gp = g + (size_t)r * ld + c;
        bf16_t* lp = lds + w * PER_WAVE + i * 512;   // wave-uniform base; HW adds lane*16B
        __builtin_amdgcn_global_load_lds(
            (const __attribute__((address_space(1))) void*)gp,
            (__attribute__((address_space(3))) void*)lp, 16, 0, 0);
    }
}

// f32 operand, split: issue global loads early ...
template<int NELEM>
DEVI void load_f32(f32x4* r, const float* __restrict__ g, int ld, int tid)
{
    constexpr int NI = NELEM / (NT * 8);
#pragma unroll
    for (int i = 0; i < NI; ++i) {
        const int eoff = i * NT * 8 + tid * 8;
        const int rr = eoff >> 6, c = eoff & 63;     // c is 8-aligned
        const float* gp = g + (size_t)rr * ld + c;
        r[2 * i]     = *(const f32x4*)(gp);
        r[2 * i + 1] = *(const f32x4*)(gp + 4);
    }
}

// ... cvt + swizzled ds_write late (after the MFMA block)
template<int NELEM>
DEVI void write_f32(bf16_t* lds, const f32x4* r, int tid)
{
    constexpr int NI = NELEM / (NT * 8);
#pragma unroll
    for (int i = 0; i < NI; ++i) {
        const int eoff = i * NT * 8 + tid * 8;
        const int rr = eoff >> 6, c = eoff & 63;
        bf16x8 h;
        h[0] = (bf16_t)r[2 * i][0]; h[1] = (bf16_t)r[2 * i][1];
        h[2] = (bf16_t)r[2 * i][2]; h[3] = (bf16_t)r[2 * i][3];
        h[4] = (bf16_t)r[2 * i + 1][0]; h[5] = (bf16_t)r[2 * i + 1][1];
        h[6] = (bf16_t)r[2 * i + 1][2]; h[7] = (bf16_t)r[2 * i + 1][3];
        const int cs = (c & 56) ^ ((rr & 7) << 3);
        *(bf16x8*)(lds + rr * 64 + cs) = h;
    }
}

#define SCHED_FENCE __builtin_amdgcn_sched_barrier(0)

// ============ expert GEMM: EOT[m][e*C+c] = sum_d WT_e[m][d]*front_e[c][d] + b ============
// R3 geometry + drain-late double-buffer (issue t+1 before MFMA(t), one sync/iter).
__global__ __launch_bounds__(NT, 4)
void expert_gemm(const bf16_t* __restrict__ WT, const float* __restrict__ inputs,
                 bf16_t* __restrict__ EOT, const float* __restrict__ expert_b)
{
    __shared__ bf16_t As[2][BM * BK];
    __shared__ bf16_t Bs[2][BN * BK];
    const int tid = threadIdx.x;

    // T1: bijective XCD-chunked swizzle. nwg = 512 -> chunk k = expert k.
    int id = blockIdx.x + 8 * (blockIdx.y + 8 * blockIdx.z);
    id = (id & 7) * 64 + (id >> 3);
    const int bx = id & 7, by = (id >> 3) & 7, e = id >> 6;

    const int brow = by * BM;   // DOUT
    const int bcol = bx * BN;   // C
    const bf16_t* A = WT + (size_t)e * DOUT * DIN + (size_t)brow * DIN;
    const float*  B = inputs + (size_t)e * C_ * DIN + (size_t)bcol * DIN;

    const int w = tid >> 6, l = tid & 63;
    const int wr = (w >> 1) * 32, wc = (w & 1) * 64;   // wave tile 32x64
    const int lr = l & 15, lk = l >> 4, sw = (l & 7) << 3;

    f32x4 acc[2][4] = {};
    f32x4 r[4];

    // prologue: fully stage tile 0 into buffer 0
    stage_bf16<BM * BK>(As[0], A, DIN, tid);
    load_f32<BN * BK>(r, B, DIN, tid);
    write_f32<BN * BK>(Bs[0], r, tid);
    __syncthreads();

    int cur = 0;
    for (int k0 = 0; k0 < DIN; k0 += BK) {
        const bool more = (k0 + BK < DIN);
        if (more) {
            stage_bf16<BM * BK>(As[cur ^ 1], A + k0 + BK, DIN, tid);   // DMA issue (async)
            load_f32<BN * BK>(r, B + k0 + BK, DIN, tid);               // global->reg issue
        }
        SCHED_FENCE;
#pragma unroll
        for (int kk = 0; kk < 2; ++kk) {
            const int cs = (kk * 32 + lk * 8) ^ sw;
            bf16x8 a[2], b[4];
#pragma unroll
            for (int m = 0; m < 2; ++m)
                a[m] = *(const bf16x8*)(&As[cur][(wr + m * 16 + lr) * BK + cs]);
#pragma unroll
            for (int n = 0; n < 4; ++n)
                b[n] = *(const bf16x8*)(&Bs[cur][(wc + n * 16 + lr) * BK + cs]);
#pragma unroll
            for (int m = 0; m < 2; ++m)
#pragma unroll
                for (int n = 0; n < 4; ++n)
                    acc[m][n] = __builtin_amdgcn_mfma_f32_16x16x32_bf16(a[m], b[n], acc[m][n], 0, 0, 0);
        }
        SCHED_FENCE;
        if (more) write_f32<BN * BK>(Bs[cur ^ 1], r, tid);   // cvt + ds_write late
        __syncthreads();                                     // drain-late: loads flew under MFMA
        cur ^= 1;
    }

    // C/D frag: col=lane&15, row=(lane>>4)*4+j ; write EOT swizzled (K-dim = ec)
#pragma unroll
    for (int m = 0; m < 2; ++m) {
#pragma unroll
        for (int n = 0; n < 4; ++n) {
            const int col = bcol + wc + n * 16 + lr;     // C index
#pragma unroll
            for (int j = 0; j < 4; ++j) {
                const int row = brow + wr + m * 16 + lk * 4 + j;   // DOUT index
                const int ec = e * C_ + col;
                EOT[(size_t)row * EC + swz(row, ec)] =
                    (bf16_t)(acc[m][n][j] + expert_b[e * DOUT + row]);
            }
        }
    }
}

// ============ fused combine+residual GEMM, z-split K, atomic blend ============
// R3 geometry + drain-late double-buffer.
// z=0: out += w0 * sum_{ec<4096}  cw[s][ec]   * EOT[m][ec]
// z=1: out += w0 * sum_{ec>=4096} cw[s][ec]   * EOT[m][ec]
// z=2: out += w1 * (sum_d x[s][d] * RWT[m][d] + residual_b[m])
__global__ __launch_bounds__(NT, 4)
void combine_gemm(const float* __restrict__ cw, const bf16_t* __restrict__ EOT,
                  const float* __restrict__ xtail, const bf16_t* __restrict__ RWT,
                  const float* __restrict__ residual_b, const float* __restrict__ rw,
                  float* __restrict__ out)
{
    __shared__ bf16_t As[2][BM * BK];   // f32-sourced (cw or x), M = tokens
    __shared__ bf16_t Bs[2][BN * BK];   // bf16 ws (EOT or RWT), N = DOUT
    const int tid = threadIdx.x;

    // T1: bijective XCD-chunked swizzle. nwg = 768 -> 96 logical ids per XCD.
    int id = blockIdx.x + 8 * (blockIdx.y + 32 * blockIdx.z);
    id = (id & 7) * 96 + (id >> 3);
    const int bx = id & 7, by = (id >> 3) & 31, z = id >> 8;

    const int brow = by * BM;   // token
    const int bcol = bx * BN;   // DOUT

    const float* A;
    const bf16_t* B;
    int ld;
    if (z == 0)      { A = cw + (size_t)brow * EC;        B = EOT + (size_t)bcol * EC;        ld = EC; }
    else if (z == 1) { A = cw + (size_t)brow * EC + 4096; B = EOT + (size_t)bcol * EC + 4096; ld = EC; }
    else             { A = xtail + (size_t)brow * DIN;    B = RWT + (size_t)bcol * DIN;       ld = DIN; }

    const int w = tid >> 6, l = tid & 63;
    const int wr = (w >> 1) * 32, wc = (w & 1) * 64;   // wave tile 32x64
    const int lr = l & 15, lk = l >> 4, sw = (l & 7) << 3;

    f32x4 acc[2][4] = {};
    f32x4 r[4];

    // prologue: fully stage tile 0 into buffer 0
    stage_bf16<BN * BK>(Bs[0], B, ld, tid);
    load_f32<BM * BK>(r, A, ld, tid);
    write_f32<BM * BK>(As[0], r, tid);
    __syncthreads();

    int cur = 0;
    for (int k0 = 0; k0 < 4096; k0 += BK) {
        const bool more = (k0 + BK < 4096);
        if (more) {
            stage_bf16<BN * BK>(Bs[cur ^ 1], B + k0 + BK, ld, tid);   // DMA issue (async)
            load_f32<BM * BK>(r, A + k0 + BK, ld, tid);               // global->reg issue
        }
        SCHED_FENCE;
#pragma unroll
        for (int kk = 0; kk < 2; ++kk) {
            const int cs = (kk * 32 + lk * 8) ^ sw;
            bf16x8 a[2], b[4];
#pragma unroll
            for (int m = 0; m < 2; ++m)
                a[m] = *(const bf16x8*)(&As[cur][(wr + m * 16 + lr) * BK + cs]);
#pragma unroll
            for (int n = 0; n < 4; ++n)
                b[n] = *(const bf16x8*)(&Bs[cur][(wc + n * 16 + lr) * BK + cs]);
#pragma unroll
            for (int m = 0; m < 2; ++m)
#pragma unroll
                for (int n = 0; n < 4; ++n)
                    acc[m][n] = __builtin_amdgcn_mfma_f32_16x16x32_bf16(a[m], b[n], acc[m][n], 0, 0, 0);
        }
        SCHED_FENCE;
        if (more) write_f32<BM * BK>(As[cur ^ 1], r, tid);   // cvt + ds_write late
        __syncthreads();                                     // drain-late
        cur ^= 1;
    }

#pragma unroll
    for (int m = 0; m < 2; ++m) {
#pragma unroll
        for (int n = 0; n < 4; ++n) {
            const int col = bcol + wc + n * 16 + lr;     // DOUT
#pragma unroll
            for (int j = 0; j < 4; ++j) {
                const int row = brow + wr + m * 16 + lk * 4 + j;   // token
                float v = acc[m][n][j];
                if (z == 2) v += residual_b[col];
                const float scale = rw[2 * row + (z == 2 ? 1 : 0)];
                atomicAdd(&out[(size_t)row * DOUT + col], scale * v);
            }
        }
    }
}

extern "C" void kernel_launch(void* const* d_in, const int* in_sizes, int n_in,
                              void* d_out, int out_size, void* d_ws, size_t ws_size,
                              hipStream_t stream)
{
    const float* inputs     = (const float*)d_in[0];
    const float* expert_w   = (const float*)d_in[1];
    const float* expert_b   = (const float*)d_in[2];
    const float* residual_w = (const float*)d_in[3];
    const float* residual_b = (const float*)d_in[4];
    const float* combine_w  = (const float*)d_in[5];
    const float* resid_wt   = (const float*)d_in[6];
    float* out = (float*)d_out;
    char* ws = (char*)d_ws;

    bf16_t* WT  = (bf16_t*)(ws + WS_WT);
    bf16_t* RWT = (bf16_t*)(ws + WS_RWT);
    bf16_t* EOT = (bf16_t*)(ws + WS_EOT);

    // 0) zero the output (blend accumulates atomically)
    hipMemsetAsync(d_out, 0, (size_t)out_size * sizeof(float), stream);

    // 1) weights -> bf16 transposed + swizzled
    transpose_cast_kernel<<<dim3(32, 128, 9), dim3(32, 8), 0, stream>>>(
        expert_w, residual_w, WT, RWT);

    // 2) expert GEMM -> EOT (bf16, swizzled, [DOUT][EC])
    expert_gemm<<<dim3(C_ / BN, DOUT / BM, E_), NT, 0, stream>>>(
        WT, inputs, EOT, expert_b);

    // 3) fused combine (K split in 2) + residual, atomic blend into out
    combine_gemm<<<dim3(DOUT / BN, TOK / BM, 3), NT, 0, stream>>>(
        combine_w, EOT, inputs + (size_t)E_ * C_ * DIN, RWT,
        residual_b, resid_wt, out);
}